// Round 1
// baseline (770.479 us; speedup 1.0000x reference)
//
#include <hip/hip_runtime.h>
#include <math.h>

constexpr int C   = 64;
constexpr int CP  = 65;     // padded leading dim for x tiles
constexpr int HID = 128;
constexpr float LEAKY = 0.2f;

// Precompute wv[v][c] = sum_h W[c][h] * a_v[h]  for the 12 attention vectors.
__global__ void prep_kernel(const float* __restrict__ W,
    const float* a0, const float* a1, const float* a2,  const float* a3,
    const float* a4, const float* a5, const float* a6,  const float* a7,
    const float* a8, const float* a9, const float* a10, const float* a11,
    float* __restrict__ wv)
{
    const float* as[12] = {a0,a1,a2,a3,a4,a5,a6,a7,a8,a9,a10,a11};
    const float* a = as[blockIdx.x];
    int c = threadIdx.x;   // 64 threads
    float s = 0.f;
    #pragma unroll
    for (int h = 0; h < HID; ++h) s += W[c*HID + h] * a[h];
    wv[blockIdx.x * C + c] = s;
}

// One block = one graph. SPATIAL: g=b*64+t, rows are joints (25).
// Temporal: g=b*25+j, rows are timesteps (64).
template<bool SPATIAL, int N0, int N1, int N2>
__launch_bounds__(256)
__global__ void branch_kernel(const float* __restrict__ src,
                              const float* __restrict__ wvec_g,   // [6][64] ws0,wd0,ws1,wd1,ws2,wd2
                              const float* __restrict__ Wp0, const float* __restrict__ b0,
                              const float* __restrict__ Wp1, const float* __restrict__ b1,
                              float* __restrict__ out)
{
    constexpr int NT  = 256;
    constexpr int N0P = N0 + 1, N1P = N1 + 1, N2P = N2 + 1;

    __shared__ float x0 [N0*CP];
    __shared__ float A0 [N0*N0P];   // attn0, becomes fusion in-place
    __shared__ float P0 [N0*N1P];   // x0@Wp0 -> M1 -> M2
    __shared__ float S0 [N0*N1P];
    __shared__ float x1 [N1*CP];
    __shared__ float A1 [N1*N1P];
    __shared__ float P1 [N1*N2P];
    __shared__ float S1 [N1*N2P];
    __shared__ float A2 [N2*N2P];
    __shared__ float S01[N0*N2P];
    __shared__ float sv[N0], tv[N0];
    __shared__ float rx[N0], rs[N0];
    __shared__ float wv[6*C];

    const int tid = threadIdx.x;
    const int g   = blockIdx.x;

    for (int i = tid; i < 6*C; i += NT) wv[i] = wvec_g[i];

    int b, inner;
    if (SPATIAL) { b = g >> 6; inner = g & 63; }   // inner = t
    else         { b = g / 25; inner = g % 25; }   // inner = j

    // load x0[row][c] from src[b][c][t][j]
    for (int i = tid; i < N0*C; i += NT) {
        int c = i / N0, r = i - c*N0;
        int off;
        if (SPATIAL) off = ((b*64 + c)*64 + inner)*25 + r;
        else         off = ((b*64 + c)*64 + r)*25 + inner;
        x0[r*CP + c] = src[off];
    }
    __syncthreads();

    // s0/t0 = x0 . ws0/wd0
    for (int p = tid; p < N0; p += NT) {
        float s = 0.f, t = 0.f;
        #pragma unroll
        for (int c = 0; c < C; ++c) {
            float xv = x0[p*CP + c];
            s += xv * wv[c];
            t += xv * wv[C + c];
        }
        sv[p] = s; tv[p] = t;
    }
    __syncthreads();

    // attn0 = leaky(s[p]+t[q])
    for (int i = tid; i < N0*N0; i += NT) {
        int p = i / N0, q = i - p*N0;
        float f = sv[p] + tv[q];
        A0[p*N0P + q] = f > 0.f ? f : LEAKY*f;
    }
    __syncthreads();

    // P0 = x0 @ Wp0   [N0][N1]
    for (int i = tid; i < N0*N1; i += NT) {
        int p = i / N1, k = i - p*N1;
        float acc = 0.f;
        #pragma unroll
        for (int c = 0; c < C; ++c) acc += x0[p*CP + c] * Wp0[c*N1 + k];
        P0[p*N1P + k] = acc;
    }
    __syncthreads();

    // S0 = softmax_rows(A0 @ P0 + b0)
    for (int i = tid; i < N0*N1; i += NT) {
        int p = i / N1, k = i - p*N1;
        float acc = b0[k];
        #pragma unroll
        for (int m = 0; m < N0; ++m) acc += A0[p*N0P + m] * P0[m*N1P + k];
        S0[p*N1P + k] = acc;
    }
    __syncthreads();
    for (int p = tid; p < N0; p += NT) {
        float mx = -1e30f;
        #pragma unroll
        for (int k = 0; k < N1; ++k) mx = fmaxf(mx, S0[p*N1P+k]);
        float sm = 0.f;
        #pragma unroll
        for (int k = 0; k < N1; ++k) { float e = expf(S0[p*N1P+k]-mx); S0[p*N1P+k] = e; sm += e; }
        float inv = 1.f/sm;
        #pragma unroll
        for (int k = 0; k < N1; ++k) S0[p*N1P+k] *= inv;
    }
    __syncthreads();

    // x1 = S0^T @ x0   [N1][C]
    for (int i = tid; i < N1*C; i += NT) {
        int k = i / C, c = i - k*C;
        float acc = 0.f;
        #pragma unroll
        for (int p = 0; p < N0; ++p) acc += S0[p*N1P + k] * x0[p*CP + c];
        x1[k*CP + c] = acc;
    }
    __syncthreads();

    // s1/t1
    for (int p = tid; p < N1; p += NT) {
        float s = 0.f, t = 0.f;
        #pragma unroll
        for (int c = 0; c < C; ++c) {
            float xv = x1[p*CP + c];
            s += xv * wv[2*C + c];
            t += xv * wv[3*C + c];
        }
        sv[p] = s; tv[p] = t;
    }
    __syncthreads();

    // attn1
    for (int i = tid; i < N1*N1; i += NT) {
        int p = i / N1, q = i - p*N1;
        float f = sv[p] + tv[q];
        A1[p*N1P + q] = f > 0.f ? f : LEAKY*f;
    }
    __syncthreads();

    // P1 = x1 @ Wp1 [N1][N2]
    for (int i = tid; i < N1*N2; i += NT) {
        int p = i / N2, k = i - p*N2;
        float acc = 0.f;
        #pragma unroll
        for (int c = 0; c < C; ++c) acc += x1[p*CP + c] * Wp1[c*N2 + k];
        P1[p*N2P + k] = acc;
    }
    __syncthreads();

    // S1 = softmax_rows(A1 @ P1 + b1)
    for (int i = tid; i < N1*N2; i += NT) {
        int p = i / N2, k = i - p*N2;
        float acc = b1[k];
        #pragma unroll
        for (int m = 0; m < N1; ++m) acc += A1[p*N1P + m] * P1[m*N2P + k];
        S1[p*N2P + k] = acc;
    }
    __syncthreads();
    for (int p = tid; p < N1; p += NT) {
        float mx = -1e30f;
        #pragma unroll
        for (int k = 0; k < N2; ++k) mx = fmaxf(mx, S1[p*N2P+k]);
        float sm = 0.f;
        #pragma unroll
        for (int k = 0; k < N2; ++k) { float e = expf(S1[p*N2P+k]-mx); S1[p*N2P+k] = e; sm += e; }
        float inv = 1.f/sm;
        #pragma unroll
        for (int k = 0; k < N2; ++k) S1[p*N2P+k] *= inv;
    }
    __syncthreads();

    // u/v = x1 . ws2/wd2  (x2 never materialized: s2 = S1^T @ u)
    for (int p = tid; p < N1; p += NT) {
        float s = 0.f, t = 0.f;
        #pragma unroll
        for (int c = 0; c < C; ++c) {
            float xv = x1[p*CP + c];
            s += xv * wv[4*C + c];
            t += xv * wv[5*C + c];
        }
        sv[p] = s; tv[p] = t;
    }
    __syncthreads();
    for (int k = tid; k < N2; k += NT) {
        float s = 0.f, t = 0.f;
        #pragma unroll
        for (int n = 0; n < N1; ++n) { s += S1[n*N2P + k]*sv[n]; t += S1[n*N2P + k]*tv[n]; }
        rx[k] = s; rs[k] = t;
    }
    __syncthreads();

    // attn2
    for (int i = tid; i < N2*N2; i += NT) {
        int p = i / N2, q = i - p*N2;
        float f = rx[p] + rs[q];
        A2[p*N2P + q] = f > 0.f ? f : LEAKY*f;
    }
    __syncthreads();

    // M1 = S0 @ A1  (into P0)
    for (int i = tid; i < N0*N1; i += NT) {
        int p = i / N1, k = i - p*N1;
        float acc = 0.f;
        #pragma unroll
        for (int m = 0; m < N1; ++m) acc += S0[p*N1P + m] * A1[m*N1P + k];
        P0[p*N1P + k] = acc;
    }
    __syncthreads();

    // fusion += M1 @ S0^T (in place on A0)
    for (int i = tid; i < N0*N0; i += NT) {
        int p = i / N0, q = i - p*N0;
        float acc = 0.f;
        #pragma unroll
        for (int k = 0; k < N1; ++k) acc += P0[p*N1P + k] * S0[q*N1P + k];
        A0[p*N0P + q] += acc;
    }
    __syncthreads();

    // S01 = S0 @ S1 [N0][N2]
    for (int i = tid; i < N0*N2; i += NT) {
        int p = i / N2, k = i - p*N2;
        float acc = 0.f;
        #pragma unroll
        for (int m = 0; m < N1; ++m) acc += S0[p*N1P + m] * S1[m*N2P + k];
        S01[p*N2P + k] = acc;
    }
    __syncthreads();

    // M2 = S01 @ A2  (into P0)
    for (int i = tid; i < N0*N2; i += NT) {
        int p = i / N2, k = i - p*N2;
        float acc = 0.f;
        #pragma unroll
        for (int m = 0; m < N2; ++m) acc += S01[p*N2P + m] * A2[m*N2P + k];
        P0[p*N2P + k] = acc;
    }
    __syncthreads();

    // fusion += M2 @ S01^T
    for (int i = tid; i < N0*N0; i += NT) {
        int p = i / N0, q = i - p*N0;
        float acc = 0.f;
        #pragma unroll
        for (int k = 0; k < N2; ++k) acc += P0[p*N2P + k] * S01[q*N2P + k];
        A0[p*N0P + q] += acc;
    }
    __syncthreads();

    // final row softmax of fusion, write out
    for (int p = tid; p < N0; p += NT) {
        float mx = -1e30f;
        #pragma unroll
        for (int q = 0; q < N0; ++q) mx = fmaxf(mx, A0[p*N0P+q]);
        float sm = 0.f;
        #pragma unroll
        for (int q = 0; q < N0; ++q) sm += expf(A0[p*N0P+q] - mx);
        rx[p] = mx; rs[p] = 1.f/sm;
    }
    __syncthreads();
    size_t base = (size_t)g * (N0*N0);
    for (int i = tid; i < N0*N0; i += NT) {
        int p = i / N0, q = i - p*N0;
        out[base + i] = expf(A0[p*N0P + q] - rx[p]) * rs[p];
    }
}

extern "C" void kernel_launch(void* const* d_in, const int* in_sizes, int n_in,
                              void* d_out, int out_size, void* d_ws, size_t ws_size,
                              hipStream_t stream) {
    const float* src = (const float*)d_in[0];
    const float* W   = (const float*)d_in[1];
    // dict order: src, W, (as_src0, as_dst0, at_src0, at_dst0) x3, Wsp0,bsp0,Wsp1,bsp1,Wtp0,btp0,Wtp1,btp1
    float* wv = (float*)d_ws;   // [12][64]: spatial ws0,wd0,ws1,wd1,ws2,wd2 then temporal same

    prep_kernel<<<12, 64, 0, stream>>>(W,
        (const float*)d_in[2],  (const float*)d_in[3],    // as_src0, as_dst0
        (const float*)d_in[6],  (const float*)d_in[7],    // as_src1, as_dst1
        (const float*)d_in[10], (const float*)d_in[11],   // as_src2, as_dst2
        (const float*)d_in[4],  (const float*)d_in[5],    // at_src0, at_dst0
        (const float*)d_in[8],  (const float*)d_in[9],    // at_src1, at_dst1
        (const float*)d_in[12], (const float*)d_in[13],   // at_src2, at_dst2
        wv);

    float* out = (float*)d_out;
    // spatial: 256*64 = 16384 graphs of 25 nodes
    branch_kernel<true, 25, 12, 5><<<16384, 256, 0, stream>>>(
        src, wv,
        (const float*)d_in[14], (const float*)d_in[15],
        (const float*)d_in[16], (const float*)d_in[17],
        out);
    // temporal: 256*25 = 6400 graphs of 64 nodes; output offset = 256*64*25*25
    branch_kernel<false, 64, 32, 16><<<6400, 256, 0, stream>>>(
        src, wv + 6*64,
        (const float*)d_in[18], (const float*)d_in[19],
        (const float*)d_in[20], (const float*)d_in[21],
        out + 10240000);
}

// Round 2
// 504.885 us; speedup vs baseline: 1.5260x; 1.5260x over previous
//
#include <hip/hip_runtime.h>
#include <math.h>

constexpr int HID = 128;
constexpr float LEAKY = 0.2f;

__device__ __forceinline__ float4 ldf4(const float* p){ return *reinterpret_cast<const float4*>(p); }
__device__ __forceinline__ void stf4(float* p, float4 v){ *reinterpret_cast<float4*>(p) = v; }
__device__ __forceinline__ float dot4(float4 a, float4 b){ return a.x*b.x + a.y*b.y + a.z*b.z + a.w*b.w; }
__device__ __forceinline__ float4 fma4(float s, float4 b, float4 acc){
    acc.x += s*b.x; acc.y += s*b.y; acc.z += s*b.z; acc.w += s*b.w; return acc;
}
__device__ __forceinline__ float lrelu(float f){ return f > 0.f ? f : LEAKY*f; }

// Precompute wv[v][c] = sum_h W[c][h] * a_v[h] for the 12 attention vectors.
__global__ void prep_kernel(const float* __restrict__ W,
    const float* a0, const float* a1, const float* a2,  const float* a3,
    const float* a4, const float* a5, const float* a6,  const float* a7,
    const float* a8, const float* a9, const float* a10, const float* a11,
    float* __restrict__ wv)
{
    const float* as[12] = {a0,a1,a2,a3,a4,a5,a6,a7,a8,a9,a10,a11};
    const float* a = as[blockIdx.x];
    int c = threadIdx.x;   // 64 threads
    float s = 0.f;
    #pragma unroll
    for (int h = 0; h < HID; ++h) s += W[c*HID + h] * a[h];
    wv[blockIdx.x * 64 + c] = s;
}

// One block = one graph. SPATIAL: g=b*64+t (rows=25 joints). Temporal: g=b*25+j (rows=64 steps).
template<bool SPATIAL, int NT, int N0, int N1, int N2>
__launch_bounds__(NT, 4)
__global__ void branch_kernel(const float* __restrict__ src,
                              const float* __restrict__ wvec_g,   // [6][64]
                              const float* __restrict__ Wp0, const float* __restrict__ b0,
                              const float* __restrict__ Wp1, const float* __restrict__ b1,
                              float* __restrict__ out, int nwg_div8)
{
    constexpr int C = 64, CP = 68;
    constexpr int A0P = SPATIAL ? 28 : 68;   // strides chosen: %32 spreads rows across banks, 16B-aligned
    constexpr int N1R = SPATIAL ? 16 : 36;
    constexpr int N2R = SPATIAL ? 8  : 20;
    constexpr int SV  = (N0 + 3) & ~3;
    static_assert(SPATIAL || (NT == 512 && N0 == 64), "temporal reg-block assumes 512 thr");

    // tenants of the x0 region (alive only after x0 is dead)
    constexpr int oA1 = 0;
    constexpr int oP1 = oA1 + N1*N1R;
    constexpr int oS1 = oP1 + N1*N2R;
    constexpr int oA2 = oS1 + N1*N2R;
    constexpr int oS01= oA2 + N2*N2R;
    static_assert(oS01 + N0*N2R <= N0*CP, "xr region overflow");
    constexpr int PRsz = (N0*N1R > N1*CP) ? N0*N1R : N1*CP;   // P0 -> x1 -> M1 -> M2

    __shared__ __align__(16) float xr[N0*CP];
    __shared__ __align__(16) float A0[N0*A0P];   // attn0 -> fusion (in place)
    __shared__ __align__(16) float PR[PRsz];
    __shared__ __align__(16) float S0[N0*N1R];
    __shared__ __align__(16) float sv[SV], tv[SV], rx[SV], rs[SV];
    __shared__ __align__(16) float wv[6*C];

    const int tid = threadIdx.x;
    const int g = (blockIdx.x & 7) * nwg_div8 + (blockIdx.x >> 3);  // XCD-contiguous swizzle

    int b, inner;
    if constexpr (SPATIAL) { b = g >> 6; inner = g & 63; }
    else                   { b = g / 25; inner = g - b*25; }

    for (int i = tid; i < 6*C; i += NT) wv[i] = wvec_g[i];
    if constexpr (SPATIAL) {
        for (int i = tid; i < N0*C; i += NT) {
            int c = i / N0, r = i - c*N0;
            xr[r*CP + c] = src[((b*64 + c)*64 + inner)*25 + r];
        }
    } else {
        for (int i = tid; i < N0*C; i += NT) {
            int c = i >> 6, r = i & 63;
            xr[r*CP + c] = src[((b*64 + c)*64 + r)*25 + inner];
        }
    }
    __syncthreads();

    // ---- phase 1: {s0,t0 | P0 = x0@Wp0} ----
    for (int i = tid; i < 2*N0; i += NT) {
        int which = i / N0, p = i - which*N0;
        const float* w = wv + which*C;
        float acc = 0.f;
        #pragma unroll
        for (int c = 0; c < C; c += 4) acc += dot4(ldf4(&xr[p*CP + c]), ldf4(&w[c]));
        if (which) tv[p] = acc; else sv[p] = acc;
    }
    for (int i = tid; i < N0*(N1/4); i += NT) {
        int p = i / (N1/4), k4 = i - p*(N1/4);
        float4 acc = {0,0,0,0};
        #pragma unroll
        for (int c = 0; c < C; ++c) acc = fma4(xr[p*CP + c], ldf4(&Wp0[c*N1 + 4*k4]), acc);
        stf4(&PR[p*N1R + 4*k4], acc);
    }
    __syncthreads();

    // ---- phase 2: A0 = leaky(s+t^T) ----
    if constexpr (N0 % 4 == 0) {
        for (int i = tid; i < N0*(N0/4); i += NT) {
            int p = i / (N0/4), q4 = i - p*(N0/4);
            float s = sv[p]; float4 t = ldf4(&tv[4*q4]);
            float4 r; r.x=lrelu(s+t.x); r.y=lrelu(s+t.y); r.z=lrelu(s+t.z); r.w=lrelu(s+t.w);
            stf4(&A0[p*A0P + 4*q4], r);
        }
    } else {
        for (int i = tid; i < N0*N0; i += NT) {
            int p = i / N0, q = i - p*N0;
            A0[p*A0P + q] = lrelu(sv[p] + tv[q]);
        }
    }
    __syncthreads();

    // ---- phase 3: S0raw = A0@P0 + b0 ----
    for (int i = tid; i < N0*(N1/4); i += NT) {
        int p = i / (N1/4), k4 = i - p*(N1/4);
        float4 acc = ldf4(&b0[4*k4]);
        #pragma unroll
        for (int m = 0; m < N0; ++m) acc = fma4(A0[p*A0P + m], ldf4(&PR[m*N1R + 4*k4]), acc);
        stf4(&S0[p*N1R + 4*k4], acc);
    }
    __syncthreads();

    // ---- phase 4: row softmax S0 ----
    for (int p = tid; p < N0; p += NT) {
        float mx = -1e30f;
        #pragma unroll
        for (int k = 0; k < N1; ++k) mx = fmaxf(mx, S0[p*N1R + k]);
        float sm = 0.f;
        #pragma unroll
        for (int k = 0; k < N1; ++k) { float e = __expf(S0[p*N1R + k] - mx); S0[p*N1R + k] = e; sm += e; }
        float inv = 1.f / sm;
        #pragma unroll
        for (int k = 0; k < N1; ++k) S0[p*N1R + k] *= inv;
    }
    __syncthreads();

    // ---- phase 5: x1 = S0^T @ x0  (into PR) ----
    for (int i = tid; i < N1*(C/4); i += NT) {
        int k = i / (C/4), c4 = i - k*(C/4);
        float4 acc = {0,0,0,0};
        #pragma unroll
        for (int p = 0; p < N0; ++p) acc = fma4(S0[p*N1R + k], ldf4(&xr[p*CP + 4*c4]), acc);
        stf4(&PR[k*CP + 4*c4], acc);
    }
    __syncthreads();

    // ---- phase 6: {s1,t1 | P1 = x1@Wp1} ----
    for (int i = tid; i < 2*N1; i += NT) {
        int which = i / N1, p = i - which*N1;
        const float* w = wv + (2 + which)*C;
        float acc = 0.f;
        #pragma unroll
        for (int c = 0; c < C; c += 4) acc += dot4(ldf4(&PR[p*CP + c]), ldf4(&w[c]));
        if (which) tv[p] = acc; else sv[p] = acc;
    }
    if constexpr (N2 % 4 == 0) {
        for (int i = tid; i < N1*(N2/4); i += NT) {
            int p = i / (N2/4), k4 = i - p*(N2/4);
            float4 acc = {0,0,0,0};
            #pragma unroll
            for (int c = 0; c < C; ++c) acc = fma4(PR[p*CP + c], ldf4(&Wp1[c*N2 + 4*k4]), acc);
            stf4(&xr[oP1 + p*N2R + 4*k4], acc);
        }
    } else {
        for (int i = tid; i < N1*N2; i += NT) {
            int p = i / N2, k = i - p*N2;
            float acc = 0.f;
            #pragma unroll
            for (int c = 0; c < C; ++c) acc += PR[p*CP + c] * Wp1[c*N2 + k];
            xr[oP1 + p*N2R + k] = acc;
        }
    }
    __syncthreads();

    // ---- phase 7: A1 ----
    for (int i = tid; i < N1*N1; i += NT) {
        int p = i / N1, q = i - p*N1;
        xr[oA1 + p*N1R + q] = lrelu(sv[p] + tv[q]);
    }
    __syncthreads();

    // ---- phase 8: S1raw = A1@P1 + b1 ----
    if constexpr (N2 % 4 == 0) {
        for (int i = tid; i < N1*(N2/4); i += NT) {
            int p = i / (N2/4), k4 = i - p*(N2/4);
            float4 acc = ldf4(&b1[4*k4]);
            #pragma unroll
            for (int m = 0; m < N1; ++m) acc = fma4(xr[oA1 + p*N1R + m], ldf4(&xr[oP1 + m*N2R + 4*k4]), acc);
            stf4(&xr[oS1 + p*N2R + 4*k4], acc);
        }
    } else {
        for (int i = tid; i < N1*N2; i += NT) {
            int p = i / N2, k = i - p*N2;
            float acc = b1[k];
            #pragma unroll
            for (int m = 0; m < N1; ++m) acc += xr[oA1 + p*N1R + m] * xr[oP1 + m*N2R + k];
            xr[oS1 + p*N2R + k] = acc;
        }
    }
    __syncthreads();

    // ---- phase 9: {row softmax S1 | u,v = x1 . ws2/wd2} ----
    for (int p = tid; p < N1; p += NT) {
        float mx = -1e30f;
        #pragma unroll
        for (int k = 0; k < N2; ++k) mx = fmaxf(mx, xr[oS1 + p*N2R + k]);
        float sm = 0.f;
        #pragma unroll
        for (int k = 0; k < N2; ++k) { float e = __expf(xr[oS1 + p*N2R + k] - mx); xr[oS1 + p*N2R + k] = e; sm += e; }
        float inv = 1.f / sm;
        #pragma unroll
        for (int k = 0; k < N2; ++k) xr[oS1 + p*N2R + k] *= inv;
    }
    for (int i = tid; i < 2*N1; i += NT) {
        int which = i / N1, p = i - which*N1;
        const float* w = wv + (4 + which)*C;
        float acc = 0.f;
        #pragma unroll
        for (int c = 0; c < C; c += 4) acc += dot4(ldf4(&PR[p*CP + c]), ldf4(&w[c]));
        if (which) tv[p] = acc; else sv[p] = acc;
    }
    __syncthreads();

    // ---- phase 10: rx/rs = S1^T . (u,v) ----
    for (int k = tid; k < N2; k += NT) {
        float a = 0.f, c2 = 0.f;
        #pragma unroll
        for (int n = 0; n < N1; ++n) { float s1 = xr[oS1 + n*N2R + k]; a += s1*sv[n]; c2 += s1*tv[n]; }
        rx[k] = a; rs[k] = c2;
    }
    __syncthreads();

    // ---- phase 11: {A2 | M1 = S0@A1 (into PR)} ----
    for (int i = tid; i < N2*N2; i += NT) {
        int p = i / N2, q = i - p*N2;
        xr[oA2 + p*N2R + q] = lrelu(rx[p] + rs[q]);
    }
    for (int i = tid; i < N0*(N1/4); i += NT) {
        int p = i / (N1/4), k4 = i - p*(N1/4);
        float4 acc = {0,0,0,0};
        #pragma unroll
        for (int m = 0; m < N1; ++m) acc = fma4(S0[p*N1R + m], ldf4(&xr[oA1 + m*N1R + 4*k4]), acc);
        stf4(&PR[p*N1R + 4*k4], acc);
    }
    __syncthreads();

    // ---- phase 12: {fusion += M1@S0^T | S01 = S0@S1} ----
    if constexpr (!SPATIAL) {
        {
            int q = tid & 63, pg = tid >> 6;
            float4 s0r[8];
            #pragma unroll
            for (int j = 0; j < 8; ++j) s0r[j] = ldf4(&S0[q*N1R + 4*j]);
            #pragma unroll
            for (int pi = 0; pi < 8; ++pi) {
                int p = pg*8 + pi;
                float acc = 0.f;
                #pragma unroll
                for (int j = 0; j < 8; ++j) acc += dot4(ldf4(&PR[p*N1R + 4*j]), s0r[j]);
                A0[p*A0P + q] += acc;
            }
        }
        for (int i = tid; i < N0*(N2/4); i += NT) {
            int p = i / (N2/4), k4 = i - p*(N2/4);
            float4 acc = {0,0,0,0};
            #pragma unroll
            for (int m = 0; m < N1; ++m) acc = fma4(S0[p*N1R + m], ldf4(&xr[oS1 + m*N2R + 4*k4]), acc);
            stf4(&xr[oS01 + p*N2R + 4*k4], acc);
        }
    } else {
        for (int i = tid; i < N0*N0; i += NT) {
            int p = i / N0, q = i - p*N0;
            float acc = 0.f;
            #pragma unroll
            for (int j = 0; j < N1/4; ++j) acc += dot4(ldf4(&PR[p*N1R + 4*j]), ldf4(&S0[q*N1R + 4*j]));
            A0[p*A0P + q] += acc;
        }
        for (int i = tid; i < N0*N2; i += NT) {
            int p = i / N2, k = i - p*N2;
            float acc = 0.f;
            #pragma unroll
            for (int m = 0; m < N1; ++m) acc += S0[p*N1R + m] * xr[oS1 + m*N2R + k];
            xr[oS01 + p*N2R + k] = acc;
        }
    }
    __syncthreads();

    // ---- phase 13: M2 = S01@A2 (into PR) ----
    if constexpr (N2 % 4 == 0) {
        for (int i = tid; i < N0*(N2/4); i += NT) {
            int p = i / (N2/4), k4 = i - p*(N2/4);
            float4 acc = {0,0,0,0};
            #pragma unroll
            for (int m = 0; m < N2; ++m) acc = fma4(xr[oS01 + p*N2R + m], ldf4(&xr[oA2 + m*N2R + 4*k4]), acc);
            stf4(&PR[p*N2R + 4*k4], acc);
        }
    } else {
        for (int i = tid; i < N0*N2; i += NT) {
            int p = i / N2, k = i - p*N2;
            float acc = 0.f;
            #pragma unroll
            for (int m = 0; m < N2; ++m) acc += xr[oS01 + p*N2R + m] * xr[oA2 + m*N2R + k];
            PR[p*N2R + k] = acc;
        }
    }
    __syncthreads();

    // ---- phase 14: fusion += M2@S01^T ----
    if constexpr (!SPATIAL) {
        int q = tid & 63, pg = tid >> 6;
        float4 sr[4];
        #pragma unroll
        for (int j = 0; j < 4; ++j) sr[j] = ldf4(&xr[oS01 + q*N2R + 4*j]);
        #pragma unroll
        for (int pi = 0; pi < 8; ++pi) {
            int p = pg*8 + pi;
            float acc = 0.f;
            #pragma unroll
            for (int j = 0; j < 4; ++j) acc += dot4(ldf4(&PR[p*N2R + 4*j]), sr[j]);
            A0[p*A0P + q] += acc;
        }
    } else {
        for (int i = tid; i < N0*N0; i += NT) {
            int p = i / N0, q = i - p*N0;
            float acc = 0.f;
            #pragma unroll
            for (int m = 0; m < N2; ++m) acc += PR[p*N2R + m] * xr[oS01 + q*N2R + m];
            A0[p*A0P + q] += acc;
        }
    }
    __syncthreads();

    // ---- phase 15: final row-softmax stats ----
    for (int p = tid; p < N0; p += NT) {
        float mx = -1e30f;
        #pragma unroll
        for (int q = 0; q < N0; ++q) mx = fmaxf(mx, A0[p*A0P + q]);
        float sm = 0.f;
        #pragma unroll
        for (int q = 0; q < N0; ++q) sm += __expf(A0[p*A0P + q] - mx);
        rx[p] = mx; rs[p] = 1.f / sm;
    }
    __syncthreads();

    // ---- phase 16: write ----
    if constexpr (!SPATIAL) {
        size_t base = (size_t)g * (N0*N0);
        for (int i = tid; i < N0*(N0/4); i += NT) {
            int p = i / (N0/4), q4 = i - p*(N0/4);
            float mx = rx[p], inv = rs[p];
            float4 a = ldf4(&A0[p*A0P + 4*q4]);
            float4 o; o.x=__expf(a.x-mx)*inv; o.y=__expf(a.y-mx)*inv;
                      o.z=__expf(a.z-mx)*inv; o.w=__expf(a.w-mx)*inv;
            stf4(&out[base + p*N0 + 4*q4], o);
        }
    } else {
        size_t base = (size_t)g * (N0*N0);
        for (int i = tid; i < N0*N0; i += NT) {
            int p = i / N0, q = i - p*N0;
            out[base + i] = __expf(A0[p*A0P + q] - rx[p]) * rs[p];
        }
    }
}

extern "C" void kernel_launch(void* const* d_in, const int* in_sizes, int n_in,
                              void* d_out, int out_size, void* d_ws, size_t ws_size,
                              hipStream_t stream) {
    const float* src = (const float*)d_in[0];
    const float* W   = (const float*)d_in[1];
    float* wv = (float*)d_ws;   // [12][64]: spatial ws0,wd0,ws1,wd1,ws2,wd2 then temporal same

    prep_kernel<<<12, 64, 0, stream>>>(W,
        (const float*)d_in[2],  (const float*)d_in[3],    // as_src0, as_dst0
        (const float*)d_in[6],  (const float*)d_in[7],    // as_src1, as_dst1
        (const float*)d_in[10], (const float*)d_in[11],   // as_src2, as_dst2
        (const float*)d_in[4],  (const float*)d_in[5],    // at_src0, at_dst0
        (const float*)d_in[8],  (const float*)d_in[9],    // at_src1, at_dst1
        (const float*)d_in[12], (const float*)d_in[13],   // at_src2, at_dst2
        wv);

    float* out = (float*)d_out;
    // spatial: 16384 graphs of 25 nodes
    branch_kernel<true, 256, 25, 12, 5><<<16384, 256, 0, stream>>>(
        src, wv,
        (const float*)d_in[14], (const float*)d_in[15],
        (const float*)d_in[16], (const float*)d_in[17],
        out, 16384/8);
    // temporal: 6400 graphs of 64 nodes; out offset 16384*625
    branch_kernel<false, 512, 64, 32, 16><<<6400, 512, 0, stream>>>(
        src, wv + 6*64,
        (const float*)d_in[18], (const float*)d_in[19],
        (const float*)d_in[20], (const float*)d_in[21],
        out + 10240000, 6400/8);
}